// Round 10
// baseline (189.606 us; speedup 1.0000x reference)
//
#include <hip/hip_runtime.h>
#include <hip/hip_bf16.h>

// Problem constants (AttentionConv2d): B=32, CIN=256, H=W=32 -> N=1024,
// DK=DV=128, HEADS=8 -> per-head d=16, OUT=256.
#define BATCH 32
#define CIN   256
#define NPOS  1024
#define DKC   128
#define DVC   128
#define HEADS 8
#define OUTC  256

typedef __bf16 bf16x8 __attribute__((ext_vector_type(8)));
typedef __bf16 bf16x4 __attribute__((ext_vector_type(4)));
typedef float  f32x4  __attribute__((ext_vector_type(4)));
typedef float  f32x16 __attribute__((ext_vector_type(16)));
typedef unsigned u32x4 __attribute__((ext_vector_type(4)));

// q pre-scale: dk^-0.5 * log2(e), so attention can use raw exp2.
#define QSCALE 0.3606737602f

__device__ inline bf16x8 load8(const __bf16* p) {
    return *reinterpret_cast<const bf16x8*>(p);
}
__device__ inline f32x4 fzero4() {
    f32x4 z;
#pragma unroll
    for (int i = 0; i < 4; ++i) z[i] = 0.0f;
    return z;
}
__device__ inline float fexp2(float x) {
#if __has_builtin(__builtin_amdgcn_exp2f)
    return __builtin_amdgcn_exp2f(x);
#else
    return exp2f(x);
#endif
}

// ---------------------------------------------------------------------------
// Kernel C (v3): convert weights + self-detect dtype + zero the producer-
// consumer counters for the fused kernel. fp32 mantissa-low halfwords hit
// e>=0x92 with p~0.43 over 256 samples -> P(miss) < 1e-30; bf16 N(0,0.02)
// never does. Block-uniform verdict -> identical across blocks.
// ---------------------------------------------------------------------------
#define CV_WQKV 98304                    // w_qkv 384*256 -> wcat[0..)
#define CV_WOUT (CV_WQKV + 32768)        // w_out 128*256 -> wcat[98304..)
#define CV_BQKV (CV_WOUT + 384)          // b_qkv -> bcat[0..384)
#define CV_BOUT (CV_BQKV + 128)          // b_out -> bcat[384..512)
#define CV_WATT (CV_BOUT + 16384)        // w_attn 128*128
#define CV_BATT (CV_WATT + 128)          // b_attn
__global__ __launch_bounds__(256) void convert_all(
    const void* __restrict__ w_qkv, const void* __restrict__ b_qkv,
    const void* __restrict__ w_attn, const void* __restrict__ b_attn,
    const void* __restrict__ w_out, const void* __restrict__ b_out,
    __bf16* __restrict__ wcat, __bf16* __restrict__ bcat,
    __bf16* __restrict__ w_attnc, __bf16* __restrict__ b_attnc,
    int* __restrict__ flag, int* __restrict__ counters) {
    __shared__ int s;
    if (threadIdx.x == 0) s = 0;
    __syncthreads();
    unsigned short u = ((const unsigned short*)w_qkv)[threadIdx.x];
    if (((u >> 7) & 0xFF) >= 0x92) atomicAdd(&s, 1);
    __syncthreads();
    bool isf32 = (s > 0);
    if (blockIdx.x == 0) {
        if (threadIdx.x == 0) *flag = isf32 ? 1 : 0;
        if (threadIdx.x < BATCH) counters[threadIdx.x] = 0;
    }

    int i = blockIdx.x * 256 + threadIdx.x;
    const void* src; __bf16* dst; int j;
    if      (i < CV_WQKV) { src = w_qkv;  j = i;           dst = wcat + i; }
    else if (i < CV_WOUT) { src = w_out;  j = i - CV_WQKV; dst = wcat + i; }
    else if (i < CV_BQKV) { src = b_qkv;  j = i - CV_WOUT; dst = bcat + j; }
    else if (i < CV_BOUT) { src = b_out;  j = i - CV_BQKV; dst = bcat + 384 + j; }
    else if (i < CV_WATT) { src = w_attn; j = i - CV_BOUT; dst = w_attnc + j; }
    else if (i < CV_BATT) { src = b_attn; j = i - CV_WATT; dst = b_attnc + j; }
    else return;
    if (isf32) *dst = (__bf16)((const float*)src)[j];
    else       *dst = ((const __bf16*)src)[j];
}

// ---------------------------------------------------------------------------
// FUSED producer-consumer kernel: qkv+conv GEMM phase (measured-best qkv3
// structure, 44us) then attention+projection phase (measured-best v8
// structure, 44us) in ONE launch. 512 blocks x 512 threads.
//   Mapping: b = id%32, tile = id/32 (n0 = nq0 = tile*64). id%8 = b%8 puts
//   all producers AND consumers of a batch on one XCD (perf heuristic only).
//   Sync: after qkv stores, device-visible release atomicAdd(counters[b]);
//   consumer spins on agent-scoped acquire load until ==16. Correct
//   regardless of XCD placement (scoped release/acquire, Guideline 16).
//   DEADLOCK-FREE: LDS = union(xs 33.8KB, olds 17.4KB) = 33.8KB ->
//   exactly 2 blocks/CU -> all 512 blocks co-resident before any spin.
// ---------------------------------------------------------------------------
#define OSTR 136  // olds row stride in ch (272 B, 17x16B -> conflict-free)
__global__ __launch_bounds__(512, 4) void fused_qkv_attn(
    const void* __restrict__ xv,       // [B][C][N] fp32 or bf16
    const __bf16* __restrict__ wcat,   // [512][256]
    const __bf16* __restrict__ bcat,   // [512]
    const __bf16* __restrict__ w_attn, // [128][128]
    const __bf16* __restrict__ b_attn, // [128]
    __bf16* __restrict__ q_ws,         // [B*H][N][16]
    __bf16* __restrict__ k_ws,         // [B*H][N][16]
    __bf16* __restrict__ v_ws,         // [B*H][16][N]
    void* __restrict__ out,            // [B][256][N], dtype per flag
    const int* __restrict__ flag,
    int* __restrict__ counters)        // [B] producer counters
{
    __shared__ __align__(16) char smem[64 * 264 * 2];  // 33792 B, phase union
    __bf16 (*xs)[264]  = reinterpret_cast<__bf16(*)[264]>(smem);
    __bf16 (*olds)[OSTR] = reinterpret_cast<__bf16(*)[OSTR]>(smem);

    bool isf32 = (*flag != 0);
    int id  = blockIdx.x;
    int b   = id & 31;          // id%8 == b%8 -> XCD-affine per batch
    int n0  = (id >> 5) * 64;   // tile 0..15
    int t   = threadIdx.x;

    // ======================= PHASE 1: qkv+conv GEMM ========================
    {
        int nl = t & 63, cb = t >> 6;
#pragma unroll
        for (int cs = 0; cs < 32; ++cs) {
            int c = cs * 8 + cb;
            size_t gi = ((size_t)b * CIN + c) * NPOS + n0 + nl;
            float v = isf32 ? ((const float*)xv)[gi] : (float)((const __bf16*)xv)[gi];
            xs[nl][c] = (__bf16)v;
        }
    }
    __syncthreads();

    int wave = t >> 6;
    int lane = t & 63;
    int quad = lane >> 4, colid = lane & 15;
    {
        int row0 = (wave >> 2) * 256 + (wave & 3) * 64;
        const __bf16* wp = wcat + (size_t)(row0 + colid) * CIN + quad * 8;

        f32x4 acc[4][4];
#pragma unroll
        for (int rt = 0; rt < 4; ++rt)
#pragma unroll
            for (int st = 0; st < 4; ++st) acc[rt][st] = fzero4();

#pragma unroll
        for (int k0 = 0; k0 < CIN; k0 += 32) {
            bf16x8 aA[4], bB[4];
#pragma unroll
            for (int rt = 0; rt < 4; ++rt)
                aA[rt] = load8(wp + (size_t)(rt * 16) * CIN + k0);
#pragma unroll
            for (int st = 0; st < 4; ++st)
                bB[st] = *reinterpret_cast<const bf16x8*>(&xs[st * 16 + colid][k0 + quad * 8]);
#pragma unroll
            for (int rt = 0; rt < 4; ++rt)
#pragma unroll
                for (int st = 0; st < 4; ++st)
                    acc[rt][st] = __builtin_amdgcn_mfma_f32_16x16x32_bf16(aA[rt], bB[st], acc[rt][st], 0, 0, 0);
        }

#pragma unroll
        for (int rt = 0; rt < 4; ++rt) {
            int obase = row0 + rt * 16;
            float bias[4];
#pragma unroll
            for (int r = 0; r < 4; ++r) bias[r] = (float)bcat[obase + quad * 4 + r];

            if (obase < DKC) {                       // ---- q: [B*H][N][16]
                int h = obase >> 4;
                __bf16* qb = q_ws + (((size_t)b * HEADS + h) * NPOS + n0) * 16 + quad * 4;
#pragma unroll
                for (int st = 0; st < 4; ++st) {
                    bf16x4 ov;
#pragma unroll
                    for (int r = 0; r < 4; ++r)
                        ov[r] = (__bf16)((acc[rt][st][r] + bias[r]) * QSCALE);
                    *reinterpret_cast<bf16x4*>(qb + (size_t)(st * 16 + colid) * 16) = ov;
                }
            } else if (obase < 2 * DKC) {            // ---- k: [B*H][N][16]
                int h = (obase - DKC) >> 4;
                __bf16* kb = k_ws + (((size_t)b * HEADS + h) * NPOS + n0) * 16 + quad * 4;
#pragma unroll
                for (int st = 0; st < 4; ++st) {
                    bf16x4 ov;
#pragma unroll
                    for (int r = 0; r < 4; ++r)
                        ov[r] = (__bf16)(acc[rt][st][r] + bias[r]);
                    *reinterpret_cast<bf16x4*>(kb + (size_t)(st * 16 + colid) * 16) = ov;
                }
            } else if (obase < 384) {                // ---- v: [B*H][16][N]
                int h = (obase - 2 * DKC) >> 4;
                __bf16* vb = v_ws + (((size_t)b * HEADS + h) * 16 + quad * 4) * NPOS + n0 + colid;
#pragma unroll
                for (int r = 0; r < 4; ++r)
#pragma unroll
                    for (int st = 0; st < 4; ++st)
                        vb[(size_t)r * NPOS + st * 16] = (__bf16)(acc[rt][st][r] + bias[r]);
            } else {                                  // ---- conv out
                int oc = obase - 384 + quad * 4;
#pragma unroll
                for (int r = 0; r < 4; ++r) {
                    size_t ob = ((size_t)b * OUTC + oc + r) * NPOS + n0 + colid;
#pragma unroll
                    for (int st = 0; st < 4; ++st) {
                        float v = acc[rt][st][r] + bias[r];
                        if (isf32) __builtin_nontemporal_store(v, (float*)out + ob + st * 16);
                        else       __builtin_nontemporal_store((__bf16)v, (__bf16*)out + ob + st * 16);
                    }
                }
            }
        }
    }

    // ============ producer-consumer handoff (device-scope visible) =========
    __syncthreads();   // all waves' stores issued & drained (vmcnt0 at barrier)
    if (t == 0) {
        // release: publish this tile's q/k/v to device scope, then count it.
        __hip_atomic_fetch_add(&counters[b], 1, __ATOMIC_RELEASE,
                               __HIP_MEMORY_SCOPE_AGENT);
        // acquire-spin until all 16 tiles of batch b are published.
        while (__hip_atomic_load(&counters[b], __ATOMIC_ACQUIRE,
                                 __HIP_MEMORY_SCOPE_AGENT) < 16)
            __builtin_amdgcn_s_sleep(2);
    }
    __syncthreads();   // xs reads done by all waves; olds writes may begin

    // ================== PHASE 2: attention + projection ====================
    int nq0 = n0;
    int h   = wave;
    int bh  = b * HEADS + h;
    int l5  = lane & 31, hi = lane >> 5;

    const __bf16* qp = q_ws + (size_t)bh * NPOS * 16;
    const __bf16* kp = k_ws + (size_t)bh * NPOS * 16;
    const __bf16* vp = v_ws + (size_t)bh * 16 * NPOS;

    bf16x8 qB0 = load8(qp + (size_t)(nq0 + l5) * 16 + hi * 8);
    bf16x8 qB1 = load8(qp + (size_t)(nq0 + 32 + l5) * 16 + hi * 8);

    bf16x8 vA0, vA1;
#pragma unroll
    for (int i = 0; i < 8; ++i) { vA0[i] = (__bf16)1.0f; vA1[i] = (__bf16)1.0f; }
    const __bf16* vrow = vp + (size_t)l5 * NPOS + hi * 8;  // valid when l5<16

    f32x16 zero16;
#pragma unroll
    for (int i = 0; i < 16; ++i) zero16[i] = 0.0f;
    f32x16 acc0 = zero16, acc1 = zero16;

    bf16x8 kA = load8(kp + (size_t)l5 * 16 + hi * 8);
    if (l5 < 16) {
        vA0 = load8(vrow);
        vA1 = load8(vrow + 16);
    }

#pragma unroll 2
    for (int nk0 = 0; nk0 < NPOS; nk0 += 32) {
        int nkn = (nk0 + 32) & (NPOS - 1);
        bf16x8 kA_n = load8(kp + (size_t)(nkn + l5) * 16 + hi * 8);
        bf16x8 vA0_n = vA0, vA1_n = vA1;
        if (l5 < 16) {
            vA0_n = load8(vrow + nkn);
            vA1_n = load8(vrow + nkn + 16);
        }
#pragma unroll
        for (int half = 0; half < 2; ++half) {
            f32x16 st = __builtin_amdgcn_mfma_f32_32x32x16_bf16(
                kA, half ? qB1 : qB0, zero16, 0, 0, 0);
            unsigned w[8];
#pragma unroll
            for (int m = 0; m < 4; ++m) {
                float e0 = fexp2(st[4 * m + 0]);
                float e1 = fexp2(st[4 * m + 1]);
                float e2 = fexp2(st[4 * m + 2]);
                float e3 = fexp2(st[4 * m + 3]);
                unsigned lo, hw;
                asm("v_cvt_pk_bf16_f32 %0, %1, %2" : "=v"(lo) : "v"(e0), "v"(e1));
                asm("v_cvt_pk_bf16_f32 %0, %1, %2" : "=v"(hw) : "v"(e2), "v"(e3));
                w[2 * m]     = lo;
                w[2 * m + 1] = hw;
            }
            asm("v_permlane32_swap_b32 %0, %1" : "+v"(w[0]), "+v"(w[2]));
            asm("v_permlane32_swap_b32 %0, %1" : "+v"(w[1]), "+v"(w[3]));
            asm("v_permlane32_swap_b32 %0, %1" : "+v"(w[4]), "+v"(w[6]));
            asm("v_permlane32_swap_b32 %0, %1" : "+v"(w[5]), "+v"(w[7]));
            u32x4 t1 = {w[0], w[1], w[2], w[3]};
            u32x4 t2 = {w[4], w[5], w[6], w[7]};
            bf16x8 pB1 = __builtin_bit_cast(bf16x8, t1);
            bf16x8 pB2 = __builtin_bit_cast(bf16x8, t2);
            if (half) {
                acc1 = __builtin_amdgcn_mfma_f32_32x32x16_bf16(vA0, pB1, acc1, 0, 0, 0);
                acc1 = __builtin_amdgcn_mfma_f32_32x32x16_bf16(vA1, pB2, acc1, 0, 0, 0);
            } else {
                acc0 = __builtin_amdgcn_mfma_f32_32x32x16_bf16(vA0, pB1, acc0, 0, 0, 0);
                acc0 = __builtin_amdgcn_mfma_f32_32x32x16_bf16(vA1, pB2, acc0, 0, 0, 0);
            }
        }
        kA = kA_n; vA0 = vA0_n; vA1 = vA1_n;
    }
#pragma unroll
    for (int half = 0; half < 2; ++half) {
        const f32x16& acc = half ? acc1 : acc0;
        float inv = 1.0f / acc[8];
        bf16x4 o0, o1;
#pragma unroll
        for (int r = 0; r < 4; ++r) {
            o0[r] = (__bf16)(acc[r] * inv);       // dv = r + 4*hi
            o1[r] = (__bf16)(acc[4 + r] * inv);   // dv = 8 + r + 4*hi
        }
        __bf16* ol = &olds[32 * half + l5][h * 16 + 4 * hi];
        *reinterpret_cast<bf16x4*>(ol)     = o0;
        *reinterpret_cast<bf16x4*>(ol + 8) = o1;
    }
    __syncthreads();

    // ---- projection: wave computes out-channels [h*16, h*16+16) x 64 q.
    {
        int row0 = h * 16;
        f32x4 pacc[4];
#pragma unroll
        for (int st = 0; st < 4; ++st) pacc[st] = fzero4();
#pragma unroll
        for (int k0 = 0; k0 < DVC; k0 += 32) {
            bf16x8 a = load8(w_attn + (size_t)(row0 + colid) * DVC + k0 + quad * 8);
#pragma unroll
            for (int st = 0; st < 4; ++st) {
                bf16x8 bb = *reinterpret_cast<const bf16x8*>(&olds[st * 16 + colid][k0 + quad * 8]);
                pacc[st] = __builtin_amdgcn_mfma_f32_16x16x32_bf16(a, bb, pacc[st], 0, 0, 0);
            }
        }
#pragma unroll
        for (int r = 0; r < 4; ++r) {
            int o = row0 + quad * 4 + r;
            float bias = (float)b_attn[o];
#pragma unroll
            for (int st = 0; st < 4; ++st) {
                int n = nq0 + st * 16 + colid;
                float v = pacc[st][r] + bias;
                size_t oi = ((size_t)b * OUTC + DVC + o) * NPOS + n;
                if (isf32) __builtin_nontemporal_store(v, (float*)out + oi);
                else       __builtin_nontemporal_store((__bf16)v, (__bf16*)out + oi);
            }
        }
    }
}

// ---------------------------------------------------------------------------
// Workspace layout (bytes):
//   0       : flag (int)           256 : counters (int[32])
//   1.00 MB : wcat [512][256] (256 KB)   1.50 MB : bcat [512]
//   1.75 MB : w_attnc (32 KB)            2.00 MB : b_attnc
//   28 MB   : q_ws (8 MB)   36 MB : k_ws (8 MB)   44 MB : v_ws (8 MB)
// ---------------------------------------------------------------------------
extern "C" void kernel_launch(void* const* d_in, const int* in_sizes, int n_in,
                              void* d_out, int out_size, void* d_ws, size_t ws_size,
                              hipStream_t stream) {
    const void* x      = d_in[0];
    const void* w_qkv  = d_in[1];
    const void* b_qkv  = d_in[2];
    const void* w_attn = d_in[3];
    const void* b_attn = d_in[4];
    const void* w_out  = d_in[5];
    const void* b_out  = d_in[6];

    char* ws = (char*)d_ws;
    int*    flag     = (int*)ws;
    int*    counters = (int*)(ws + 256);
    __bf16* wcat     = (__bf16*)(ws + (1u << 20));
    __bf16* bcat     = (__bf16*)(ws + (3u << 19));
    __bf16* w_attnc  = (__bf16*)(ws + (7u << 18));
    __bf16* b_attnc  = (__bf16*)(ws + (1u << 21));
    __bf16* q_ws     = (__bf16*)(ws + (28u << 20));
    __bf16* k_ws     = (__bf16*)(ws + (36u << 20));
    __bf16* v_ws     = (__bf16*)(ws + (44u << 20));

    convert_all<<<(CV_BATT + 255) / 256, 256, 0, stream>>>(
        w_qkv, b_qkv, w_attn, b_attn, w_out, b_out,
        wcat, bcat, w_attnc, b_attnc, flag, counters);

    fused_qkv_attn<<<dim3(512), 512, 0, stream>>>(
        x, wcat, bcat, w_attnc, b_attnc, q_ws, k_ws, v_ws, d_out, flag, counters);
}

// Round 11
// 146.849 us; speedup vs baseline: 1.2912x; 1.2912x over previous
//
#include <hip/hip_runtime.h>
#include <hip/hip_bf16.h>

// Problem constants (AttentionConv2d): B=32, CIN=256, H=W=32 -> N=1024,
// DK=DV=128, HEADS=8 -> per-head d=16, OUT=256.
#define BATCH 32
#define CIN   256
#define NPOS  1024
#define DKC   128
#define DVC   128
#define HEADS 8
#define OUTC  256

typedef __bf16 bf16x8 __attribute__((ext_vector_type(8)));
typedef __bf16 bf16x4 __attribute__((ext_vector_type(4)));
typedef float  f32x4  __attribute__((ext_vector_type(4)));
typedef float  f32x16 __attribute__((ext_vector_type(16)));
typedef unsigned u32x4 __attribute__((ext_vector_type(4)));

// q pre-scale: dk^-0.5 * log2(e), so attention can use raw exp2.
#define QSCALE 0.3606737602f

__device__ inline bf16x8 load8(const __bf16* p) {
    return *reinterpret_cast<const bf16x8*>(p);
}
__device__ inline f32x4 fzero4() {
    f32x4 z;
#pragma unroll
    for (int i = 0; i < 4; ++i) z[i] = 0.0f;
    return z;
}
__device__ inline float fexp2(float x) {
#if __has_builtin(__builtin_amdgcn_exp2f)
    return __builtin_amdgcn_exp2f(x);
#else
    return exp2f(x);
#endif
}

// ---------------------------------------------------------------------------
// Kernel C (v2): convert weights + SELF-DETECT dtype (round-9 version,
// proven). Every block scans the first 256 halfwords of w_qkv: fp32
// mantissa-low halfwords hit e>=0x92 with p~0.43 -> P(miss) < 1e-30;
// bf16 N(0,0.02) never does. Block-uniform verdict; block 0 publishes flag.
// ---------------------------------------------------------------------------
#define CV_WQKV 98304                    // w_qkv 384*256 -> wcat[0..)
#define CV_WOUT (CV_WQKV + 32768)        // w_out 128*256 -> wcat[98304..)
#define CV_BQKV (CV_WOUT + 384)          // b_qkv -> bcat[0..384)
#define CV_BOUT (CV_BQKV + 128)          // b_out -> bcat[384..512)
#define CV_WATT (CV_BOUT + 16384)        // w_attn 128*128
#define CV_BATT (CV_WATT + 128)          // b_attn
__global__ __launch_bounds__(256) void convert_all(
    const void* __restrict__ w_qkv, const void* __restrict__ b_qkv,
    const void* __restrict__ w_attn, const void* __restrict__ b_attn,
    const void* __restrict__ w_out, const void* __restrict__ b_out,
    __bf16* __restrict__ wcat, __bf16* __restrict__ bcat,
    __bf16* __restrict__ w_attnc, __bf16* __restrict__ b_attnc,
    int* __restrict__ flag) {
    __shared__ int s;
    if (threadIdx.x == 0) s = 0;
    __syncthreads();
    unsigned short u = ((const unsigned short*)w_qkv)[threadIdx.x];
    if (((u >> 7) & 0xFF) >= 0x92) atomicAdd(&s, 1);
    __syncthreads();
    bool isf32 = (s > 0);
    if (blockIdx.x == 0 && threadIdx.x == 0) *flag = isf32 ? 1 : 0;

    int i = blockIdx.x * 256 + threadIdx.x;
    const void* src; __bf16* dst; int j;
    if      (i < CV_WQKV) { src = w_qkv;  j = i;           dst = wcat + i; }
    else if (i < CV_WOUT) { src = w_out;  j = i - CV_WQKV; dst = wcat + i; }
    else if (i < CV_BQKV) { src = b_qkv;  j = i - CV_WOUT; dst = bcat + j; }
    else if (i < CV_BOUT) { src = b_out;  j = i - CV_BQKV; dst = bcat + 384 + j; }
    else if (i < CV_WATT) { src = w_attn; j = i - CV_BOUT; dst = w_attnc + j; }
    else if (i < CV_BATT) { src = b_attn; j = i - CV_WATT; dst = b_attnc + j; }
    else return;
    if (isf32) *dst = (__bf16)((const float*)src)[j];
    else       *dst = ((const __bf16*)src)[j];
}

// ---------------------------------------------------------------------------
// Kernel 1 (v9 = round-8 qkv3 + VECTORIZED STAGING): QKV+conv GEMM, fused
// x-transpose. Round-10 falsified fusion; rounds 6/9 falsified thin waves;
// round 7 falsified K-loop prefetch. The one untried Guideline-13 lever:
// staging did 32 SCALAR loads/thread (4B fp32 / 2B bf16 per lane) on the
// serial pre-barrier critical path. Now: fp32 path = float4 (16B/lane,
// 8 loads/thread, 256B contiguous per c-row across 16 lanes); bf16 path =
// bf16x8 (4 loads/thread). LDS writes unchanged (scattered b16, conflicts
// already measured tolerable). K-loop/epilogue identical to measured-best.
// grid (N/64=16, B=32) = 512 blocks, 512 thr / 8 waves x 64 rows,
// 2 blocks/CU. LDS xs[64][264] (33.8 KB), b128 reads conflict-free.
// ---------------------------------------------------------------------------
__global__ __launch_bounds__(512, 4) void qkv_conv_gemm7(
    const void* __restrict__ xv,      // [B][C][N] fp32 or bf16
    const __bf16* __restrict__ wcat,  // [512][256]
    const __bf16* __restrict__ bcat,  // [512]
    __bf16* __restrict__ q_ws,        // [B*H][N][16]
    __bf16* __restrict__ k_ws,        // [B*H][N][16]
    __bf16* __restrict__ v_ws,        // [B*H][16][N]
    void* __restrict__ out,           // [B][256][N], dtype per flag
    const int* __restrict__ flag)
{
    __shared__ __bf16 xs[64][264];    // 33792 B
    bool isf32 = (*flag != 0);
    int b   = blockIdx.y;
    int n0  = blockIdx.x * 64;
    int t   = threadIdx.x;

    if (isf32) {
        int nl4 = (t & 15) * 4, cq = t >> 4;   // 16 n-threads x 32 c-rows
#pragma unroll
        for (int cs = 0; cs < 8; ++cs) {
            int c = cs * 32 + cq;
            const float* xp = (const float*)xv + ((size_t)b * CIN + c) * NPOS + n0 + nl4;
            f32x4 v = *reinterpret_cast<const f32x4*>(xp);
#pragma unroll
            for (int j = 0; j < 4; ++j) xs[nl4 + j][c] = (__bf16)v[j];
        }
    } else {
        int nl8 = (t & 7) * 8, cq = t >> 3;    // 8 n-threads x 64 c-rows
#pragma unroll
        for (int cs = 0; cs < 4; ++cs) {
            int c = cs * 64 + cq;
            const __bf16* xp = (const __bf16*)xv + ((size_t)b * CIN + c) * NPOS + n0 + nl8;
            bf16x8 v = load8(xp);
#pragma unroll
            for (int j = 0; j < 8; ++j) xs[nl8 + j][c] = v[j];
        }
    }
    __syncthreads();

    int wave = t >> 6;
    int lane = t & 63;
    int quad = lane >> 4, colid = lane & 15;
    int row0 = (wave >> 2) * 256 + (wave & 3) * 64;

    const __bf16* wp = wcat + (size_t)(row0 + colid) * CIN + quad * 8;

    f32x4 acc[4][4];
#pragma unroll
    for (int rt = 0; rt < 4; ++rt)
#pragma unroll
        for (int st = 0; st < 4; ++st) acc[rt][st] = fzero4();

#pragma unroll
    for (int k0 = 0; k0 < CIN; k0 += 32) {
        bf16x8 aA[4], bB[4];
#pragma unroll
        for (int rt = 0; rt < 4; ++rt)
            aA[rt] = load8(wp + (size_t)(rt * 16) * CIN + k0);
#pragma unroll
        for (int st = 0; st < 4; ++st)
            bB[st] = *reinterpret_cast<const bf16x8*>(&xs[st * 16 + colid][k0 + quad * 8]);
#pragma unroll
        for (int rt = 0; rt < 4; ++rt)
#pragma unroll
            for (int st = 0; st < 4; ++st)
                acc[rt][st] = __builtin_amdgcn_mfma_f32_16x16x32_bf16(aA[rt], bB[st], acc[rt][st], 0, 0, 0);
    }

#pragma unroll
    for (int rt = 0; rt < 4; ++rt) {
        int obase = row0 + rt * 16;  // uniform per wave; 16 consecutive o
        float bias[4];
#pragma unroll
        for (int r = 0; r < 4; ++r) bias[r] = (float)bcat[obase + quad * 4 + r];

        if (obase < DKC) {                       // ---- q: [B*H][N][16]
            int h = obase >> 4;
            __bf16* qb = q_ws + (((size_t)b * HEADS + h) * NPOS + n0) * 16 + quad * 4;
#pragma unroll
            for (int st = 0; st < 4; ++st) {
                bf16x4 ov;
#pragma unroll
                for (int r = 0; r < 4; ++r)
                    ov[r] = (__bf16)((acc[rt][st][r] + bias[r]) * QSCALE);
                *reinterpret_cast<bf16x4*>(qb + (size_t)(st * 16 + colid) * 16) = ov;
            }
        } else if (obase < 2 * DKC) {            // ---- k: [B*H][N][16]
            int h = (obase - DKC) >> 4;
            __bf16* kb = k_ws + (((size_t)b * HEADS + h) * NPOS + n0) * 16 + quad * 4;
#pragma unroll
            for (int st = 0; st < 4; ++st) {
                bf16x4 ov;
#pragma unroll
                for (int r = 0; r < 4; ++r)
                    ov[r] = (__bf16)(acc[rt][st][r] + bias[r]);
                *reinterpret_cast<bf16x4*>(kb + (size_t)(st * 16 + colid) * 16) = ov;
            }
        } else if (obase < 384) {                // ---- v: [B*H][16][N]
            int h = (obase - 2 * DKC) >> 4;
            __bf16* vb = v_ws + (((size_t)b * HEADS + h) * 16 + quad * 4) * NPOS + n0 + colid;
#pragma unroll
            for (int r = 0; r < 4; ++r)
#pragma unroll
                for (int st = 0; st < 4; ++st)
                    vb[(size_t)r * NPOS + st * 16] = (__bf16)(acc[rt][st][r] + bias[r]);
        } else {                                  // ---- conv out: [B][0..128][N]
            int oc = obase - 384 + quad * 4;
#pragma unroll
            for (int r = 0; r < 4; ++r) {
                size_t ob = ((size_t)b * OUTC + oc + r) * NPOS + n0 + colid;
#pragma unroll
                for (int st = 0; st < 4; ++st) {
                    float v = acc[rt][st][r] + bias[r];
                    if (isf32) __builtin_nontemporal_store(v, (float*)out + ob + st * 16);
                    else       __builtin_nontemporal_store((__bf16)v, (__bf16*)out + ob + st * 16);
                }
            }
        }
    }
}

// ---------------------------------------------------------------------------
// Kernel 2 (v8, UNCHANGED from round 8 = measured best): fused attention +
// output projection, 64-query waves, one-window K/V register prefetch,
// nt out-stores. grid (b=32, N/64=16), block 512: wave = head.
//   XCD affinity: id = b + 32*nc -> id%8 = b%8; per-XCD K/V = 2 MB < L2.
//   QK^T: v_mfma_f32_32x32x16_bf16, C = hoisted zero16.
//   exp2 -> v_cvt_pk_bf16_f32 -> v_permlane32_swap_b32 -> PV B-frag (T12).
//   PV: A rows 0-15 = V[dv][key], rows 16-31 = 1.0 -> denominator free.
//   Epilogue: olds[64 q][128 ch] -> barrier -> 16 out-ch x 64 q per wave.
// ---------------------------------------------------------------------------
#define OSTR 136  // olds row stride in ch (272 B, 17x16B -> conflict-free)
__global__ __launch_bounds__(512, 4) void attention_kernel(
    const __bf16* __restrict__ q_ws,   // [B*H][N][16]
    const __bf16* __restrict__ k_ws,   // [B*H][N][16]
    const __bf16* __restrict__ v_ws,   // [B*H][16][N]
    const __bf16* __restrict__ w_attn, // [128][128]
    const __bf16* __restrict__ b_attn, // [128]
    void* __restrict__ out,            // [B][256][N], dtype per flag
    const int* __restrict__ flag)
{
    __shared__ __align__(16) __bf16 olds[64][OSTR];  // 17.4 KB
    int b    = blockIdx.x;
    int nq0  = blockIdx.y * 64;
    int wave = threadIdx.x >> 6;                 // = head h
    int lane = threadIdx.x & 63;
    int l5   = lane & 31, hi = lane >> 5;        // 32x32 frag coords
    int h    = wave;
    int bh   = b * HEADS + h;

    const __bf16* qp = q_ws + (size_t)bh * NPOS * 16;
    const __bf16* kp = k_ws + (size_t)bh * NPOS * 16;
    const __bf16* vp = v_ws + (size_t)bh * 16 * NPOS;

    // Two Q B-frags (32x32x16): lane holds Q[nq][hi*8 .. hi*8+7]
    bf16x8 qB0 = load8(qp + (size_t)(nq0 + l5) * 16 + hi * 8);
    bf16x8 qB1 = load8(qp + (size_t)(nq0 + 32 + l5) * 16 + hi * 8);

    // PV A-operand: rows 0-15 = V (dv = l5), rows 16-31 = 1.0 (denominator).
    bf16x8 vA0, vA1;
#pragma unroll
    for (int i = 0; i < 8; ++i) { vA0[i] = (__bf16)1.0f; vA1[i] = (__bf16)1.0f; }
    const __bf16* vrow = vp + (size_t)l5 * NPOS + hi * 8;  // valid when l5<16

    f32x16 zero16;
#pragma unroll
    for (int i = 0; i < 16; ++i) zero16[i] = 0.0f;
    f32x16 acc0 = zero16, acc1 = zero16;

    // ---- window-0 operand loads (prologue of the prefetch pipeline)
    bf16x8 kA = load8(kp + (size_t)l5 * 16 + hi * 8);
    if (l5 < 16) {
        vA0 = load8(vrow);
        vA1 = load8(vrow + 16);
    }

#pragma unroll 2
    for (int nk0 = 0; nk0 < NPOS; nk0 += 32) {
        // ---- prefetch window n+1 (wraps to 0 on the last iteration)
        int nkn = (nk0 + 32) & (NPOS - 1);
        bf16x8 kA_n = load8(kp + (size_t)(nkn + l5) * 16 + hi * 8);
        bf16x8 vA0_n = vA0, vA1_n = vA1;   // lanes l5>=16 keep the 1.0 rows
        if (l5 < 16) {
            vA0_n = load8(vrow + nkn);
            vA1_n = load8(vrow + nkn + 16);
        }
        // ---- compute window n with the already-resident kA/vA0/vA1
#pragma unroll
        for (int half = 0; half < 2; ++half) {
            f32x16 st = __builtin_amdgcn_mfma_f32_32x32x16_bf16(
                kA, half ? qB1 : qB0, zero16, 0, 0, 0);
            // st[reg]: key = nk0+(reg&3)+8*(reg>>2)+4*hi, query = nq0+32*half+l5
            unsigned w[8];
#pragma unroll
            for (int m = 0; m < 4; ++m) {
                float e0 = fexp2(st[4 * m + 0]);
                float e1 = fexp2(st[4 * m + 1]);
                float e2 = fexp2(st[4 * m + 2]);
                float e3 = fexp2(st[4 * m + 3]);
                unsigned lo, hw;
                asm("v_cvt_pk_bf16_f32 %0, %1, %2" : "=v"(lo) : "v"(e0), "v"(e1));
                asm("v_cvt_pk_bf16_f32 %0, %1, %2" : "=v"(hw) : "v"(e2), "v"(e3));
                w[2 * m]     = lo;
                w[2 * m + 1] = hw;
            }
            // Swap lane-halves: {w0..w3} = B-frag keys nk0+0..15,
            // {w4..w7} = keys nk0+16..31 (per-lane keys hi*8..hi*8+7).
            asm("v_permlane32_swap_b32 %0, %1" : "+v"(w[0]), "+v"(w[2]));
            asm("v_permlane32_swap_b32 %0, %1" : "+v"(w[1]), "+v"(w[3]));
            asm("v_permlane32_swap_b32 %0, %1" : "+v"(w[4]), "+v"(w[6]));
            asm("v_permlane32_swap_b32 %0, %1" : "+v"(w[5]), "+v"(w[7]));
            u32x4 t1 = {w[0], w[1], w[2], w[3]};
            u32x4 t2 = {w[4], w[5], w[6], w[7]};
            bf16x8 pB1 = __builtin_bit_cast(bf16x8, t1);
            bf16x8 pB2 = __builtin_bit_cast(bf16x8, t2);
            if (half) {
                acc1 = __builtin_amdgcn_mfma_f32_32x32x16_bf16(vA0, pB1, acc1, 0, 0, 0);
                acc1 = __builtin_amdgcn_mfma_f32_32x32x16_bf16(vA1, pB2, acc1, 0, 0, 0);
            } else {
                acc0 = __builtin_amdgcn_mfma_f32_32x32x16_bf16(vA0, pB1, acc0, 0, 0, 0);
                acc0 = __builtin_amdgcn_mfma_f32_32x32x16_bf16(vA1, pB2, acc0, 0, 0, 0);
            }
        }
        // ---- rotate
        kA = kA_n; vA0 = vA0_n; vA1 = vA1_n;
    }
    // acc rows: (reg&3)+8*(reg>>2)+4*hi, col = query = l5.
    // regs 0-7 -> rows 0-15 = O^T[dv][query]; regs 8-15 -> rows 16-31 = denom.
    // Normalize and deposit this head's 16 dv channels into olds[q][h*16+dv].
#pragma unroll
    for (int half = 0; half < 2; ++half) {
        const f32x16& acc = half ? acc1 : acc0;
        float inv = 1.0f / acc[8];
        bf16x4 o0, o1;
#pragma unroll
        for (int r = 0; r < 4; ++r) {
            o0[r] = (__bf16)(acc[r] * inv);       // dv = r + 4*hi
            o1[r] = (__bf16)(acc[4 + r] * inv);   // dv = 8 + r + 4*hi
        }
        __bf16* ol = &olds[32 * half + l5][h * 16 + 4 * hi];
        *reinterpret_cast<bf16x4*>(ol)     = o0;
        *reinterpret_cast<bf16x4*>(ol + 8) = o1;
    }
    __syncthreads();

    // ---- projection: this wave computes out-channels [h*16, h*16+16) for
    // the block's 64 queries. A = w_attn rows (16B loads, L2-hot), B = olds.
    int quad = lane >> 4, colid = lane & 15;
    int row0 = h * 16;
    f32x4 pacc[4];
#pragma unroll
    for (int st = 0; st < 4; ++st) pacc[st] = fzero4();
#pragma unroll
    for (int k0 = 0; k0 < DVC; k0 += 32) {
        bf16x8 a = load8(w_attn + (size_t)(row0 + colid) * DVC + k0 + quad * 8);
#pragma unroll
        for (int st = 0; st < 4; ++st) {
            bf16x8 bb = *reinterpret_cast<const bf16x8*>(&olds[st * 16 + colid][k0 + quad * 8]);
            pacc[st] = __builtin_amdgcn_mfma_f32_16x16x32_bf16(a, bb, pacc[st], 0, 0, 0);
        }
    }
    bool isf32 = (*flag != 0);
#pragma unroll
    for (int r = 0; r < 4; ++r) {
        int o = row0 + quad * 4 + r;
        float bias = (float)b_attn[o];
#pragma unroll
        for (int st = 0; st < 4; ++st) {
            int n = nq0 + st * 16 + colid;
            float v = pacc[st][r] + bias;
            size_t oi = ((size_t)b * OUTC + DVC + o) * NPOS + n;
            if (isf32) __builtin_nontemporal_store(v, (float*)out + oi);
            else       __builtin_nontemporal_store((__bf16)v, (__bf16*)out + oi);
        }
    }
}

// ---------------------------------------------------------------------------
// Workspace layout (bytes):
//   0       : flag (int)
//   1.00 MB : wcat [512][256] (256 KB)   1.50 MB : bcat [512]
//   1.75 MB : w_attnc (32 KB)            2.00 MB : b_attnc
//   28 MB   : q_ws (8 MB)   36 MB : k_ws (8 MB)   44 MB : v_ws (8 MB)
// ---------------------------------------------------------------------------
extern "C" void kernel_launch(void* const* d_in, const int* in_sizes, int n_in,
                              void* d_out, int out_size, void* d_ws, size_t ws_size,
                              hipStream_t stream) {
    const void* x      = d_in[0];
    const void* w_qkv  = d_in[1];
    const void* b_qkv  = d_in[2];
    const void* w_attn = d_in[3];
    const void* b_attn = d_in[4];
    const void* w_out  = d_in[5];
    const void* b_out  = d_in[6];

    char* ws = (char*)d_ws;
    int*    flag    = (int*)ws;
    __bf16* wcat    = (__bf16*)(ws + (1u << 20));
    __bf16* bcat    = (__bf16*)(ws + (3u << 19));
    __bf16* w_attnc = (__bf16*)(ws + (7u << 18));
    __bf16* b_attnc = (__bf16*)(ws + (1u << 21));
    __bf16* q_ws    = (__bf16*)(ws + (28u << 20));
    __bf16* k_ws    = (__bf16*)(ws + (36u << 20));
    __bf16* v_ws    = (__bf16*)(ws + (44u << 20));

    convert_all<<<(CV_BATT + 255) / 256, 256, 0, stream>>>(
        w_qkv, b_qkv, w_attn, b_attn, w_out, b_out,
        wcat, bcat, w_attnc, b_attnc, flag);

    qkv_conv_gemm7<<<dim3(NPOS / 64, BATCH), 512, 0, stream>>>(
        x, wcat, bcat, q_ws, k_ws, v_ws, d_out, flag);
    attention_kernel<<<dim3(BATCH, NPOS / 64), 512, 0, stream>>>(
        q_ws, k_ws, v_ws, w_attnc, b_attnc, d_out, flag);
}